// Round 14
// baseline (288.281 us; speedup 1.0000x reference)
//
#include <hip/hip_runtime.h>

#define N_NODES_C 100000
#define N_EDGES_C 800000
#define FEATS 100
#define NCLS 50
#define GENE 20000
#define SCAN_BLK 1024
#define SCAN_NBLK ((N_NODES_C + SCAN_BLK - 1) / SCAN_BLK)   // 98
#define KPAD 128                                             // padded K (4 x 32)

typedef short bf16x8 __attribute__((ext_vector_type(8)));
typedef float f32x4  __attribute__((ext_vector_type(4)));

// bf16 helpers (RNE pack, shift-unpack)
__device__ __forceinline__ unsigned short f2bf(float f) {
    unsigned int x = __float_as_uint(f);
    return (unsigned short)((x + 0x7FFFu + ((x >> 16) & 1u)) >> 16);
}
__device__ __forceinline__ unsigned int pack2(float lo, float hi) {
    return (unsigned int)f2bf(lo) | ((unsigned int)f2bf(hi) << 16);
}
__device__ __forceinline__ float bflo(unsigned int u) { return __uint_as_float(u << 16); }
__device__ __forceinline__ float bfhi(unsigned int u) { return __uint_as_float(u & 0xFFFF0000u); }

// ---------------------------------------------------------------------------
// features f32 [N][100] -> bf16 [N][KPAD] (zero-padded)
// ---------------------------------------------------------------------------
__global__ void to_bf16_pad_kernel(const float* __restrict__ in,
                                   unsigned short* __restrict__ out) {
    int i = blockIdx.x * 256 + threadIdx.x;
    if (i >= N_NODES_C * 32) return;
    int node = i >> 5;
    int sl = i & 31;                       // uint2 slot (8B) within 256B row
    uint2 o = make_uint2(0u, 0u);
    if (sl < 25) {
        float4 v = reinterpret_cast<const float4*>(in + (size_t)node * FEATS)[sl];
        o.x = pack2(v.x, v.y);
        o.y = pack2(v.z, v.w);
    }
    reinterpret_cast<uint2*>(out + (size_t)node * KPAD)[sl] = o;
}

// ---------------------------------------------------------------------------
// Pad W1/W2 -> [112][KPAD] bf16, lin_w -> [64][KPAD] bf16 (zeros elsewhere)
// ---------------------------------------------------------------------------
__global__ void wprep_kernel(const float* __restrict__ W1,
                             const float* __restrict__ W2,
                             const float* __restrict__ LW,
                             unsigned short* __restrict__ Wp1,
                             unsigned short* __restrict__ Wp2,
                             unsigned short* __restrict__ LWp) {
    int i = blockIdx.x * 256 + threadIdx.x;
    if (i >= 112 * KPAD) return;
    int r = i >> 7;
    int c = i & 127;
    bool in100 = (r < 100) && (c < 100);
    Wp1[i] = in100 ? f2bf(W1[r * 100 + c]) : (unsigned short)0;
    Wp2[i] = in100 ? f2bf(W2[r * 100 + c]) : (unsigned short)0;
    if (r < 64) {
        LWp[i] = (r < NCLS && c < 100) ? f2bf(LW[r * 100 + c]) : (unsigned short)0;
    }
}

// ---------------------------------------------------------------------------
// Edge prep: degree count (int atomic) + per-edge scale, coalesced write.
// ---------------------------------------------------------------------------
__global__ void edge_prep_kernel(const int* __restrict__ node_ids,
                                 const int* __restrict__ src,
                                 const int* __restrict__ dst,
                                 const float* __restrict__ ew,
                                 const float* __restrict__ alpha,
                                 int* __restrict__ deg,
                                 float* __restrict__ scale) {
    int e = blockIdx.x * blockDim.x + threadIdx.x;
    if (e >= N_EDGES_C) return;
    int s = src[e];
    int d = dst[e];
    atomicAdd(&deg[d], 1);
    int sid = node_ids[s];
    int did = node_ids[d];
    int idx = GENE + 1;                        // cell-cell
    if (sid >= 0 && did < 0) idx = sid;        // gene -> cell
    else if (did >= 0 && sid < 0) idx = did;   // cell -> gene
    else if (did >= 0 && sid >= 0) idx = GENE; // gene -> gene
    scale[e] = alpha[idx] * ew[e];
}

// ---------------------------------------------------------------------------
// scan1: in-place inclusive scan per 1024-block + block totals
// ---------------------------------------------------------------------------
__global__ __launch_bounds__(1024) void scan1_kernel(int* __restrict__ deg,
                                                     int* __restrict__ bsum) {
    __shared__ int wsum[16];
    const int i = blockIdx.x * SCAN_BLK + threadIdx.x;
    const int lane = threadIdx.x & 63;
    const int wid = threadIdx.x >> 6;
    int v = (i < N_NODES_C) ? deg[i] : 0;
    #pragma unroll
    for (int d = 1; d < 64; d <<= 1) {
        int t = __shfl_up(v, d);
        if (lane >= d) v += t;
    }
    if (lane == 63) wsum[wid] = v;
    __syncthreads();
    if (wid == 0) {
        int s = (lane < 16) ? wsum[lane] : 0;
        #pragma unroll
        for (int d = 1; d < 16; d <<= 1) {
            int t = __shfl_up(s, d);
            if (lane >= d) s += t;
        }
        if (lane < 16) wsum[lane] = s;
    }
    __syncthreads();
    if (wid > 0) v += wsum[wid - 1];
    if (i < N_NODES_C) deg[i] = v;
    if (threadIdx.x == SCAN_BLK - 1) bsum[blockIdx.x] = v;
}

// ---------------------------------------------------------------------------
// scan3 (scan2 folded in)
// ---------------------------------------------------------------------------
__global__ __launch_bounds__(1024) void scan3_kernel(const int* __restrict__ incl,
                                                     const int* __restrict__ bsum,
                                                     int* __restrict__ rp,
                                                     int* __restrict__ cursor) {
    __shared__ int boff[SCAN_NBLK];
    if (threadIdx.x < SCAN_NBLK) boff[threadIdx.x] = bsum[threadIdx.x];
    __syncthreads();
    if (threadIdx.x == 0) {
        int off = 0;
        #pragma unroll 1
        for (int j = 0; j < SCAN_NBLK; ++j) { int t = boff[j]; boff[j] = off; off += t; }
    }
    __syncthreads();
    int i = blockIdx.x * SCAN_BLK + threadIdx.x;
    if (i >= N_NODES_C) return;
    int v = incl[i] + boff[blockIdx.x];
    rp[i + 1] = v;
    cursor[i + 1] = v;
    if (i == 0) { rp[0] = 0; cursor[0] = 0; }
}

// ---------------------------------------------------------------------------
// CSR fill: minimal chain — 3 coalesced loads, 1 atomic, 1 scatter.
// ---------------------------------------------------------------------------
__global__ void csr_fill_kernel(const int* __restrict__ src,
                                const int* __restrict__ dst,
                                const float* __restrict__ scale,
                                int* __restrict__ cursor,
                                int2* __restrict__ csr) {
    int e = blockIdx.x * blockDim.x + threadIdx.x;
    if (e >= N_EDGES_C) return;
    int s = src[e];
    int d = dst[e];
    float sc = scale[e];
    int pos = atomicAdd(&cursor[d], 1);
    csr[pos] = make_int2(s, __float_as_int(sc));
}

// ---------------------------------------------------------------------------
// Aggregation bf16->bf16 (stride KPAD): 2 nodes/wave, 32 lanes each own a
// uint2 (4 bf16 cols), 8-deep clamped unroll, f32 accumulate, bf16 padded
// write (lanes 25..31 store zeros -> K-pad is zero for MFMA consumers).
// ---------------------------------------------------------------------------
__global__ __launch_bounds__(256) void aggregate_kernel(
        const unsigned short* __restrict__ hin,   // [N][KPAD] bf16
        const int* __restrict__ rp,
        const int2* __restrict__ csr,
        unsigned short* __restrict__ nout) {      // [N][KPAD] bf16
    const int node = (blockIdx.x * 256 + threadIdx.x) >> 5;
    const int lane = threadIdx.x & 31;
    const int ll = (lane < 25) ? lane : 24;       // load slot, clamped
    if (node >= N_NODES_C) return;
    const int beg = rp[node];
    const int end = rp[node + 1];
    float a0 = 0.0f, a1 = 0.0f, a2 = 0.0f, a3 = 0.0f;
    for (int k = beg; k < end; k += 8) {
        int kk[8];
        #pragma unroll
        for (int i = 0; i < 8; ++i) kk[i] = min(k + i, end - 1);
        int2 e0 = csr[kk[0]];
        int2 e1 = csr[kk[1]];
        int2 e2 = csr[kk[2]];
        int2 e3 = csr[kk[3]];
        int2 e4 = csr[kk[4]];
        int2 e5 = csr[kk[5]];
        int2 e6 = csr[kk[6]];
        int2 e7 = csr[kk[7]];
        uint2 x0 = ((const uint2*)(hin + (size_t)e0.x * KPAD))[ll];
        uint2 x1 = ((const uint2*)(hin + (size_t)e1.x * KPAD))[ll];
        uint2 x2 = ((const uint2*)(hin + (size_t)e2.x * KPAD))[ll];
        uint2 x3 = ((const uint2*)(hin + (size_t)e3.x * KPAD))[ll];
        uint2 x4 = ((const uint2*)(hin + (size_t)e4.x * KPAD))[ll];
        uint2 x5 = ((const uint2*)(hin + (size_t)e5.x * KPAD))[ll];
        uint2 x6 = ((const uint2*)(hin + (size_t)e6.x * KPAD))[ll];
        uint2 x7 = ((const uint2*)(hin + (size_t)e7.x * KPAD))[ll];
        float w0 = __int_as_float(e0.y);
        float w1 = (k + 1 < end) ? __int_as_float(e1.y) : 0.0f;
        float w2 = (k + 2 < end) ? __int_as_float(e2.y) : 0.0f;
        float w3 = (k + 3 < end) ? __int_as_float(e3.y) : 0.0f;
        float w4 = (k + 4 < end) ? __int_as_float(e4.y) : 0.0f;
        float w5 = (k + 5 < end) ? __int_as_float(e5.y) : 0.0f;
        float w6 = (k + 6 < end) ? __int_as_float(e6.y) : 0.0f;
        float w7 = (k + 7 < end) ? __int_as_float(e7.y) : 0.0f;
        a0 = fmaf(bflo(x0.x), w0, a0); a1 = fmaf(bfhi(x0.x), w0, a1);
        a2 = fmaf(bflo(x0.y), w0, a2); a3 = fmaf(bfhi(x0.y), w0, a3);
        a0 = fmaf(bflo(x1.x), w1, a0); a1 = fmaf(bfhi(x1.x), w1, a1);
        a2 = fmaf(bflo(x1.y), w1, a2); a3 = fmaf(bfhi(x1.y), w1, a3);
        a0 = fmaf(bflo(x2.x), w2, a0); a1 = fmaf(bfhi(x2.x), w2, a1);
        a2 = fmaf(bflo(x2.y), w2, a2); a3 = fmaf(bfhi(x2.y), w2, a3);
        a0 = fmaf(bflo(x3.x), w3, a0); a1 = fmaf(bfhi(x3.x), w3, a1);
        a2 = fmaf(bflo(x3.y), w3, a2); a3 = fmaf(bfhi(x3.y), w3, a3);
        a0 = fmaf(bflo(x4.x), w4, a0); a1 = fmaf(bfhi(x4.x), w4, a1);
        a2 = fmaf(bflo(x4.y), w4, a2); a3 = fmaf(bfhi(x4.y), w4, a3);
        a0 = fmaf(bflo(x5.x), w5, a0); a1 = fmaf(bfhi(x5.x), w5, a1);
        a2 = fmaf(bflo(x5.y), w5, a2); a3 = fmaf(bfhi(x5.y), w5, a3);
        a0 = fmaf(bflo(x6.x), w6, a0); a1 = fmaf(bfhi(x6.x), w6, a1);
        a2 = fmaf(bflo(x6.y), w6, a2); a3 = fmaf(bfhi(x6.y), w6, a3);
        a0 = fmaf(bflo(x7.x), w7, a0); a1 = fmaf(bfhi(x7.x), w7, a1);
        a2 = fmaf(bflo(x7.y), w7, a2); a3 = fmaf(bfhi(x7.y), w7, a3);
    }
    const float invd = (end > beg) ? 1.0f / (float)(end - beg) : 0.0f;
    uint2 o = make_uint2(0u, 0u);
    if (lane < 25) {
        o.x = pack2(a0 * invd, a1 * invd);
        o.y = pack2(a2 * invd, a3 * invd);
    }
    ((uint2*)(nout + (size_t)node * KPAD))[lane] = o;
}

// ---------------------------------------------------------------------------
// MFMA dense: out[m][n] = act( sum_k A[m][k] * W[n][k] + b[n] )
// A bf16 [N][KPAD] (zero K-pad), Wp bf16 [NTILES*16][KPAD] (zero-padded).
// Grid 3125 x 128 threads (2 waves); wave computes a 16-row band x NT tiles.
// a-frag: lane holds A row (l&15), 8 contig k at (l>>4)*8 (m97 pattern).
// b-frag: same from W rows (W natural [NOUT][K] == B^T).
// D: col = l&15, row = (l>>4)*4 + reg.
// OUTBF: bf16 [N][KPAD] out with zeroed pad cols; else f32 [N][NOUT].
// ---------------------------------------------------------------------------
template <int NOUT, bool RELU, bool OUTBF>
__global__ __launch_bounds__(128) void dense_mfma_kernel(
        const unsigned short* __restrict__ A,     // [N][KPAD] bf16
        const unsigned short* __restrict__ Wp,    // [NT*16][KPAD] bf16
        const float* __restrict__ b,              // [NOUT]
        void* __restrict__ outp) {
    constexpr int NT = (NOUT == 100) ? 7 : 4;     // 16-col tiles

    const int tid = threadIdx.x;
    const int wid = tid >> 6;                     // 0,1
    const int lane = tid & 63;
    const int nl = lane & 15;
    const int kl8 = (lane >> 4) * 8;              // k offset of this lane's frag
    const int n0 = blockIdx.x * 32;
    const int arow = n0 + wid * 16 + nl;          // A row this lane loads

    // acc init = bias (C-in accumulates)
    f32x4 acc[NT];
    #pragma unroll
    for (int t = 0; t < NT; ++t) {
        int n = t * 16 + nl;
        float bt = (n < NOUT) ? b[n] : 0.0f;
        acc[t] = (f32x4){bt, bt, bt, bt};
    }

    const unsigned short* arow_p = A + (size_t)arow * KPAD + kl8;
    #pragma unroll
    for (int kk = 0; kk < 4; ++kk) {
        bf16x8 af = *(const bf16x8*)(arow_p + kk * 32);
        #pragma unroll
        for (int t = 0; t < NT; ++t) {
            bf16x8 bf = *(const bf16x8*)(Wp + (size_t)(t * 16 + nl) * KPAD + kk * 32 + kl8);
            acc[t] = __builtin_amdgcn_mfma_f32_16x16x32_bf16(af, bf, acc[t], 0, 0, 0);
        }
    }

    // Epilogue: D row = (l>>4)*4 + r within band
    const int rbase = n0 + wid * 16 + (lane >> 4) * 4;
    #pragma unroll
    for (int t = 0; t < NT; ++t) {
        const int n = t * 16 + nl;
        #pragma unroll
        for (int r = 0; r < 4; ++r) {
            float v = acc[t][r];
            if (RELU) v = fmaxf(v, 0.0f);
            const int row = rbase + r;
            if (OUTBF) {
                ((unsigned short*)outp)[(size_t)row * KPAD + n] =
                    (n < NOUT) ? f2bf(v) : (unsigned short)0;
            } else {
                if (n < NOUT) ((float*)outp)[(size_t)row * NOUT + n] = v;
            }
        }
    }
    if (OUTBF) {
        // zero pad cols [112,128) for this wave's 16 rows (4 lanes x 8B per row)
        const int zrow = n0 + wid * 16 + (lane >> 2);
        uint2* zp = (uint2*)((unsigned short*)outp + (size_t)zrow * KPAD + 112 + (lane & 3) * 4);
        *zp = make_uint2(0u, 0u);
    }
}

// ---------------------------------------------------------------------------
extern "C" void kernel_launch(void* const* d_in, const int* in_sizes, int n_in,
                              void* d_out, int out_size, void* d_ws, size_t ws_size,
                              hipStream_t stream) {
    const float* features = (const float*)d_in[0];
    const int*   node_ids = (const int*)d_in[1];
    const int*   src      = (const int*)d_in[2];
    const int*   dst      = (const int*)d_in[3];
    const float* ew       = (const float*)d_in[4];
    const float* alpha    = (const float*)d_in[5];
    const float* W1       = (const float*)d_in[6];
    const float* b1       = (const float*)d_in[7];
    const float* W2       = (const float*)d_in[8];
    const float* b2       = (const float*)d_in[9];
    const float* lin_w    = (const float*)d_in[10];
    const float* lin_b    = (const float*)d_in[11];
    float* out = (float*)d_out;

    char* ws = (char*)d_ws;
    size_t off = 0;
    auto alloc = [&](size_t bytes) {
        void* p = ws + off;
        off += (bytes + 255) & ~(size_t)255;
        return p;
    };
    int*   deg    = (int*)alloc((size_t)N_NODES_C * 4);
    int*   bsum   = (int*)alloc((size_t)SCAN_NBLK * 4);
    int*   rp     = (int*)alloc((size_t)(N_NODES_C + 1) * 4);
    int*   cursor = (int*)alloc((size_t)(N_NODES_C + 1) * 4);
    float* scale  = (float*)alloc((size_t)N_EDGES_C * 4);
    int2*  csr    = (int2*)alloc((size_t)N_EDGES_C * 8);
    unsigned short* fbf     = (unsigned short*)alloc((size_t)N_NODES_C * KPAD * 2);
    unsigned short* h1      = (unsigned short*)alloc((size_t)N_NODES_C * KPAD * 2);
    unsigned short* neigh_b = (unsigned short*)alloc((size_t)N_NODES_C * KPAD * 2);
    unsigned short* Wp1     = (unsigned short*)alloc((size_t)112 * KPAD * 2);
    unsigned short* Wp2     = (unsigned short*)alloc((size_t)112 * KPAD * 2);
    unsigned short* LWp     = (unsigned short*)alloc((size_t)64 * KPAD * 2);
    // h2 aliases fbf: fbf is dead after aggregate-1 reads it.
    unsigned short* h2 = fbf;
    (void)ws_size;

    // --- prep: conversions + CSR build ---
    hipMemsetAsync(deg, 0, (size_t)N_NODES_C * 4, stream);
    to_bf16_pad_kernel<<<(N_NODES_C * 32 + 255) / 256, 256, 0, stream>>>(features, fbf);
    wprep_kernel<<<(112 * KPAD + 255) / 256, 256, 0, stream>>>(W1, W2, lin_w, Wp1, Wp2, LWp);
    edge_prep_kernel<<<(N_EDGES_C + 255) / 256, 256, 0, stream>>>(
        node_ids, src, dst, ew, alpha, deg, scale);
    scan1_kernel<<<SCAN_NBLK, SCAN_BLK, 0, stream>>>(deg, bsum);
    scan3_kernel<<<SCAN_NBLK, SCAN_BLK, 0, stream>>>(deg, bsum, rp, cursor);
    csr_fill_kernel<<<(N_EDGES_C + 255) / 256, 256, 0, stream>>>(
        src, dst, scale, cursor, csr);

    // --- Layer 1 ---
    aggregate_kernel<<<(N_NODES_C * 32) / 256, 256, 0, stream>>>(fbf, rp, csr, neigh_b);
    dense_mfma_kernel<FEATS, true, true><<<N_NODES_C / 32, 128, 0, stream>>>(
        neigh_b, Wp1, b1, h1);

    // --- Layer 2 ---
    aggregate_kernel<<<(N_NODES_C * 32) / 256, 256, 0, stream>>>(h1, rp, csr, neigh_b);
    dense_mfma_kernel<FEATS, true, true><<<N_NODES_C / 32, 128, 0, stream>>>(
        neigh_b, Wp2, b2, h2);

    // --- Classifier ---
    dense_mfma_kernel<NCLS, false, false><<<N_NODES_C / 32, 128, 0, stream>>>(
        h2, LWp, lin_b, out);
}

// Round 15
// 279.360 us; speedup vs baseline: 1.0319x; 1.0319x over previous
//
#include <hip/hip_runtime.h>

#define N_NODES_C 100000
#define N_EDGES_C 800000
#define FEATS 100
#define NCLS 50
#define GENE 20000
#define SCAN_BLK 1024
#define SCAN_NBLK ((N_NODES_C + SCAN_BLK - 1) / SCAN_BLK)   // 98
#define KPAD 128                                             // padded K (4 x 32)
#define EDGES_PER_BLK 2048
#define CSR_GRP_BLKS ((N_EDGES_C + EDGES_PER_BLK - 1) / EDGES_PER_BLK)  // 391
#define GRP_NODES (N_NODES_C / 8)                            // 12500

typedef short bf16x8 __attribute__((ext_vector_type(8)));
typedef float f32x4  __attribute__((ext_vector_type(4)));

// bf16 helpers (RNE pack, shift-unpack)
__device__ __forceinline__ unsigned short f2bf(float f) {
    unsigned int x = __float_as_uint(f);
    return (unsigned short)((x + 0x7FFFu + ((x >> 16) & 1u)) >> 16);
}
__device__ __forceinline__ unsigned int pack2(float lo, float hi) {
    return (unsigned int)f2bf(lo) | ((unsigned int)f2bf(hi) << 16);
}
__device__ __forceinline__ float bflo(unsigned int u) { return __uint_as_float(u << 16); }
__device__ __forceinline__ float bfhi(unsigned int u) { return __uint_as_float(u & 0xFFFF0000u); }

// ---------------------------------------------------------------------------
// features f32 [N][100] -> bf16 [N][KPAD] (zero-padded)
// ---------------------------------------------------------------------------
__global__ void to_bf16_pad_kernel(const float* __restrict__ in,
                                   unsigned short* __restrict__ out) {
    int i = blockIdx.x * 256 + threadIdx.x;
    if (i >= N_NODES_C * 32) return;
    int node = i >> 5;
    int sl = i & 31;                       // uint2 slot (8B) within 256B row
    uint2 o = make_uint2(0u, 0u);
    if (sl < 25) {
        float4 v = reinterpret_cast<const float4*>(in + (size_t)node * FEATS)[sl];
        o.x = pack2(v.x, v.y);
        o.y = pack2(v.z, v.w);
    }
    reinterpret_cast<uint2*>(out + (size_t)node * KPAD)[sl] = o;
}

// ---------------------------------------------------------------------------
// Pad W1/W2 -> [112][KPAD] bf16, lin_w -> [64][KPAD] bf16 (zeros elsewhere)
// ---------------------------------------------------------------------------
__global__ void wprep_kernel(const float* __restrict__ W1,
                             const float* __restrict__ W2,
                             const float* __restrict__ LW,
                             unsigned short* __restrict__ Wp1,
                             unsigned short* __restrict__ Wp2,
                             unsigned short* __restrict__ LWp) {
    int i = blockIdx.x * 256 + threadIdx.x;
    if (i >= 112 * KPAD) return;
    int r = i >> 7;
    int c = i & 127;
    bool in100 = (r < 100) && (c < 100);
    Wp1[i] = in100 ? f2bf(W1[r * 100 + c]) : (unsigned short)0;
    Wp2[i] = in100 ? f2bf(W2[r * 100 + c]) : (unsigned short)0;
    if (r < 64) {
        LWp[i] = (r < NCLS && c < 100) ? f2bf(LW[r * 100 + c]) : (unsigned short)0;
    }
}

// ---------------------------------------------------------------------------
// Edge prep: degree count (int atomic) + per-edge scale, coalesced write.
// ---------------------------------------------------------------------------
__global__ void edge_prep_kernel(const int* __restrict__ node_ids,
                                 const int* __restrict__ src,
                                 const int* __restrict__ dst,
                                 const float* __restrict__ ew,
                                 const float* __restrict__ alpha,
                                 int* __restrict__ deg,
                                 float* __restrict__ scale) {
    int e = blockIdx.x * blockDim.x + threadIdx.x;
    if (e >= N_EDGES_C) return;
    int s = src[e];
    int d = dst[e];
    atomicAdd(&deg[d], 1);
    int sid = node_ids[s];
    int did = node_ids[d];
    int idx = GENE + 1;                        // cell-cell
    if (sid >= 0 && did < 0) idx = sid;        // gene -> cell
    else if (did >= 0 && sid < 0) idx = did;   // cell -> gene
    else if (did >= 0 && sid >= 0) idx = GENE; // gene -> gene
    scale[e] = alpha[idx] * ew[e];
}

// ---------------------------------------------------------------------------
// scan1: in-place inclusive scan per 1024-block + block totals
// ---------------------------------------------------------------------------
__global__ __launch_bounds__(1024) void scan1_kernel(int* __restrict__ deg,
                                                     int* __restrict__ bsum) {
    __shared__ int wsum[16];
    const int i = blockIdx.x * SCAN_BLK + threadIdx.x;
    const int lane = threadIdx.x & 63;
    const int wid = threadIdx.x >> 6;
    int v = (i < N_NODES_C) ? deg[i] : 0;
    #pragma unroll
    for (int d = 1; d < 64; d <<= 1) {
        int t = __shfl_up(v, d);
        if (lane >= d) v += t;
    }
    if (lane == 63) wsum[wid] = v;
    __syncthreads();
    if (wid == 0) {
        int s = (lane < 16) ? wsum[lane] : 0;
        #pragma unroll
        for (int d = 1; d < 16; d <<= 1) {
            int t = __shfl_up(s, d);
            if (lane >= d) s += t;
        }
        if (lane < 16) wsum[lane] = s;
    }
    __syncthreads();
    if (wid > 0) v += wsum[wid - 1];
    if (i < N_NODES_C) deg[i] = v;
    if (threadIdx.x == SCAN_BLK - 1) bsum[blockIdx.x] = v;
}

// ---------------------------------------------------------------------------
// scan3 (scan2 folded in)
// ---------------------------------------------------------------------------
__global__ __launch_bounds__(1024) void scan3_kernel(const int* __restrict__ incl,
                                                     const int* __restrict__ bsum,
                                                     int* __restrict__ rp,
                                                     int* __restrict__ cursor) {
    __shared__ int boff[SCAN_NBLK];
    if (threadIdx.x < SCAN_NBLK) boff[threadIdx.x] = bsum[threadIdx.x];
    __syncthreads();
    if (threadIdx.x == 0) {
        int off = 0;
        #pragma unroll 1
        for (int j = 0; j < SCAN_NBLK; ++j) { int t = boff[j]; boff[j] = off; off += t; }
    }
    __syncthreads();
    int i = blockIdx.x * SCAN_BLK + threadIdx.x;
    if (i >= N_NODES_C) return;
    int v = incl[i] + boff[blockIdx.x];
    rp[i + 1] = v;
    cursor[i + 1] = v;
    if (i == 0) { rp[0] = 0; cursor[0] = 0; }
}

// ---------------------------------------------------------------------------
// CSR fill, XCD-partitioned: group g = blockIdx&7 owns dst in
// [g*12500,(g+1)*12500). Each group scans ALL edges (reads L3-shared),
// commits only in-range -> every csr/cursor line written by one group
// (one XCD under round-robin dispatch) -> partial writes merge in its L2.
// ---------------------------------------------------------------------------
__global__ __launch_bounds__(256) void csr_fill_part_kernel(
        const int* __restrict__ src,
        const int* __restrict__ dst,
        const float* __restrict__ scale,
        int* __restrict__ cursor,
        int2* __restrict__ csr) {
    const int g   = blockIdx.x & 7;
    const int blk = blockIdx.x >> 3;
    const int lo  = g * GRP_NODES;
    const int hi  = lo + GRP_NODES;
    const int base = blk * EDGES_PER_BLK + threadIdx.x * 8;
    #pragma unroll
    for (int half = 0; half < 2; ++half) {
        const int e = base + half * 4;
        if (e >= N_EDGES_C) break;
        int4   s4 = *reinterpret_cast<const int4*>(src + e);
        int4   d4 = *reinterpret_cast<const int4*>(dst + e);
        float4 w4 = *reinterpret_cast<const float4*>(scale + e);
        const int   ss[4] = {s4.x, s4.y, s4.z, s4.w};
        const int   ds[4] = {d4.x, d4.y, d4.z, d4.w};
        const float ws[4] = {w4.x, w4.y, w4.z, w4.w};
        #pragma unroll
        for (int i = 0; i < 4; ++i) {
            if (ds[i] >= lo && ds[i] < hi) {
                int pos = atomicAdd(&cursor[ds[i]], 1);
                csr[pos] = make_int2(ss[i], __float_as_int(ws[i]));
            }
        }
    }
}

// ---------------------------------------------------------------------------
// Aggregation bf16->bf16 (stride KPAD): 2 nodes/wave, 32 lanes each own a
// uint2 (4 bf16 cols), 8-deep clamped unroll, f32 accumulate, bf16 padded
// write (lanes 25..31 store zeros -> K-pad is zero for MFMA consumers).
// ---------------------------------------------------------------------------
__global__ __launch_bounds__(256) void aggregate_kernel(
        const unsigned short* __restrict__ hin,   // [N][KPAD] bf16
        const int* __restrict__ rp,
        const int2* __restrict__ csr,
        unsigned short* __restrict__ nout) {      // [N][KPAD] bf16
    const int node = (blockIdx.x * 256 + threadIdx.x) >> 5;
    const int lane = threadIdx.x & 31;
    const int ll = (lane < 25) ? lane : 24;       // load slot, clamped
    if (node >= N_NODES_C) return;
    const int beg = rp[node];
    const int end = rp[node + 1];
    float a0 = 0.0f, a1 = 0.0f, a2 = 0.0f, a3 = 0.0f;
    for (int k = beg; k < end; k += 8) {
        int kk[8];
        #pragma unroll
        for (int i = 0; i < 8; ++i) kk[i] = min(k + i, end - 1);
        int2 e0 = csr[kk[0]];
        int2 e1 = csr[kk[1]];
        int2 e2 = csr[kk[2]];
        int2 e3 = csr[kk[3]];
        int2 e4 = csr[kk[4]];
        int2 e5 = csr[kk[5]];
        int2 e6 = csr[kk[6]];
        int2 e7 = csr[kk[7]];
        uint2 x0 = ((const uint2*)(hin + (size_t)e0.x * KPAD))[ll];
        uint2 x1 = ((const uint2*)(hin + (size_t)e1.x * KPAD))[ll];
        uint2 x2 = ((const uint2*)(hin + (size_t)e2.x * KPAD))[ll];
        uint2 x3 = ((const uint2*)(hin + (size_t)e3.x * KPAD))[ll];
        uint2 x4 = ((const uint2*)(hin + (size_t)e4.x * KPAD))[ll];
        uint2 x5 = ((const uint2*)(hin + (size_t)e5.x * KPAD))[ll];
        uint2 x6 = ((const uint2*)(hin + (size_t)e6.x * KPAD))[ll];
        uint2 x7 = ((const uint2*)(hin + (size_t)e7.x * KPAD))[ll];
        float w0 = __int_as_float(e0.y);
        float w1 = (k + 1 < end) ? __int_as_float(e1.y) : 0.0f;
        float w2 = (k + 2 < end) ? __int_as_float(e2.y) : 0.0f;
        float w3 = (k + 3 < end) ? __int_as_float(e3.y) : 0.0f;
        float w4 = (k + 4 < end) ? __int_as_float(e4.y) : 0.0f;
        float w5 = (k + 5 < end) ? __int_as_float(e5.y) : 0.0f;
        float w6 = (k + 6 < end) ? __int_as_float(e6.y) : 0.0f;
        float w7 = (k + 7 < end) ? __int_as_float(e7.y) : 0.0f;
        a0 = fmaf(bflo(x0.x), w0, a0); a1 = fmaf(bfhi(x0.x), w0, a1);
        a2 = fmaf(bflo(x0.y), w0, a2); a3 = fmaf(bfhi(x0.y), w0, a3);
        a0 = fmaf(bflo(x1.x), w1, a0); a1 = fmaf(bfhi(x1.x), w1, a1);
        a2 = fmaf(bflo(x1.y), w1, a2); a3 = fmaf(bfhi(x1.y), w1, a3);
        a0 = fmaf(bflo(x2.x), w2, a0); a1 = fmaf(bfhi(x2.x), w2, a1);
        a2 = fmaf(bflo(x2.y), w2, a2); a3 = fmaf(bfhi(x2.y), w2, a3);
        a0 = fmaf(bflo(x3.x), w3, a0); a1 = fmaf(bfhi(x3.x), w3, a1);
        a2 = fmaf(bflo(x3.y), w3, a2); a3 = fmaf(bfhi(x3.y), w3, a3);
        a0 = fmaf(bflo(x4.x), w4, a0); a1 = fmaf(bfhi(x4.x), w4, a1);
        a2 = fmaf(bflo(x4.y), w4, a2); a3 = fmaf(bfhi(x4.y), w4, a3);
        a0 = fmaf(bflo(x5.x), w5, a0); a1 = fmaf(bfhi(x5.x), w5, a1);
        a2 = fmaf(bflo(x5.y), w5, a2); a3 = fmaf(bfhi(x5.y), w5, a3);
        a0 = fmaf(bflo(x6.x), w6, a0); a1 = fmaf(bfhi(x6.x), w6, a1);
        a2 = fmaf(bflo(x6.y), w6, a2); a3 = fmaf(bfhi(x6.y), w6, a3);
        a0 = fmaf(bflo(x7.x), w7, a0); a1 = fmaf(bfhi(x7.x), w7, a1);
        a2 = fmaf(bflo(x7.y), w7, a2); a3 = fmaf(bfhi(x7.y), w7, a3);
    }
    const float invd = (end > beg) ? 1.0f / (float)(end - beg) : 0.0f;
    uint2 o = make_uint2(0u, 0u);
    if (lane < 25) {
        o.x = pack2(a0 * invd, a1 * invd);
        o.y = pack2(a2 * invd, a3 * invd);
    }
    ((uint2*)(nout + (size_t)node * KPAD))[lane] = o;
}

// ---------------------------------------------------------------------------
// MFMA dense: out[m][n] = act( sum_k A[m][k] * W[n][k] + b[n] )
// A bf16 [N][KPAD] (zero K-pad), Wp bf16 [NT*16][KPAD] (zero-padded).
// Grid 3125 x 128 threads (2 waves); wave computes a 16-row band x NT tiles.
// ---------------------------------------------------------------------------
template <int NOUT, bool RELU, bool OUTBF>
__global__ __launch_bounds__(128) void dense_mfma_kernel(
        const unsigned short* __restrict__ A,     // [N][KPAD] bf16
        const unsigned short* __restrict__ Wp,    // [NT*16][KPAD] bf16
        const float* __restrict__ b,              // [NOUT]
        void* __restrict__ outp) {
    constexpr int NT = (NOUT == 100) ? 7 : 4;     // 16-col tiles

    const int tid = threadIdx.x;
    const int wid = tid >> 6;                     // 0,1
    const int lane = tid & 63;
    const int nl = lane & 15;
    const int kl8 = (lane >> 4) * 8;              // k offset of this lane's frag
    const int n0 = blockIdx.x * 32;
    const int arow = n0 + wid * 16 + nl;          // A row this lane loads

    // acc init = bias (C-in accumulates)
    f32x4 acc[NT];
    #pragma unroll
    for (int t = 0; t < NT; ++t) {
        int n = t * 16 + nl;
        float bt = (n < NOUT) ? b[n] : 0.0f;
        acc[t] = (f32x4){bt, bt, bt, bt};
    }

    const unsigned short* arow_p = A + (size_t)arow * KPAD + kl8;
    #pragma unroll
    for (int kk = 0; kk < 4; ++kk) {
        bf16x8 af = *(const bf16x8*)(arow_p + kk * 32);
        #pragma unroll
        for (int t = 0; t < NT; ++t) {
            bf16x8 bf = *(const bf16x8*)(Wp + (size_t)(t * 16 + nl) * KPAD + kk * 32 + kl8);
            acc[t] = __builtin_amdgcn_mfma_f32_16x16x32_bf16(af, bf, acc[t], 0, 0, 0);
        }
    }

    // Epilogue: D row = (l>>4)*4 + r within band
    const int rbase = n0 + wid * 16 + (lane >> 4) * 4;
    #pragma unroll
    for (int t = 0; t < NT; ++t) {
        const int n = t * 16 + nl;
        #pragma unroll
        for (int r = 0; r < 4; ++r) {
            float v = acc[t][r];
            if (RELU) v = fmaxf(v, 0.0f);
            const int row = rbase + r;
            if (OUTBF) {
                ((unsigned short*)outp)[(size_t)row * KPAD + n] =
                    (n < NOUT) ? f2bf(v) : (unsigned short)0;
            } else {
                if (n < NOUT) ((float*)outp)[(size_t)row * NOUT + n] = v;
            }
        }
    }
    if (OUTBF) {
        // zero pad cols [112,128) for this wave's 16 rows (4 lanes x 8B per row)
        const int zrow = n0 + wid * 16 + (lane >> 2);
        uint2* zp = (uint2*)((unsigned short*)outp + (size_t)zrow * KPAD + 112 + (lane & 3) * 4);
        *zp = make_uint2(0u, 0u);
    }
}

// ---------------------------------------------------------------------------
extern "C" void kernel_launch(void* const* d_in, const int* in_sizes, int n_in,
                              void* d_out, int out_size, void* d_ws, size_t ws_size,
                              hipStream_t stream) {
    const float* features = (const float*)d_in[0];
    const int*   node_ids = (const int*)d_in[1];
    const int*   src      = (const int*)d_in[2];
    const int*   dst      = (const int*)d_in[3];
    const float* ew       = (const float*)d_in[4];
    const float* alpha    = (const float*)d_in[5];
    const float* W1       = (const float*)d_in[6];
    const float* b1       = (const float*)d_in[7];
    const float* W2       = (const float*)d_in[8];
    const float* b2       = (const float*)d_in[9];
    const float* lin_w    = (const float*)d_in[10];
    const float* lin_b    = (const float*)d_in[11];
    float* out = (float*)d_out;

    char* ws = (char*)d_ws;
    size_t off = 0;
    auto alloc = [&](size_t bytes) {
        void* p = ws + off;
        off += (bytes + 255) & ~(size_t)255;
        return p;
    };
    int*   deg    = (int*)alloc((size_t)N_NODES_C * 4);
    int*   bsum   = (int*)alloc((size_t)SCAN_NBLK * 4);
    int*   rp     = (int*)alloc((size_t)(N_NODES_C + 1) * 4);
    int*   cursor = (int*)alloc((size_t)(N_NODES_C + 1) * 4);
    float* scale  = (float*)alloc((size_t)N_EDGES_C * 4);
    int2*  csr    = (int2*)alloc((size_t)N_EDGES_C * 8);
    unsigned short* fbf     = (unsigned short*)alloc((size_t)N_NODES_C * KPAD * 2);
    unsigned short* h1      = (unsigned short*)alloc((size_t)N_NODES_C * KPAD * 2);
    unsigned short* neigh_b = (unsigned short*)alloc((size_t)N_NODES_C * KPAD * 2);
    unsigned short* Wp1     = (unsigned short*)alloc((size_t)112 * KPAD * 2);
    unsigned short* Wp2     = (unsigned short*)alloc((size_t)112 * KPAD * 2);
    unsigned short* LWp     = (unsigned short*)alloc((size_t)64 * KPAD * 2);
    // h2 aliases fbf: fbf is dead after aggregate-1 reads it.
    unsigned short* h2 = fbf;
    (void)ws_size;

    // --- prep: conversions + CSR build ---
    hipMemsetAsync(deg, 0, (size_t)N_NODES_C * 4, stream);
    to_bf16_pad_kernel<<<(N_NODES_C * 32 + 255) / 256, 256, 0, stream>>>(features, fbf);
    wprep_kernel<<<(112 * KPAD + 255) / 256, 256, 0, stream>>>(W1, W2, lin_w, Wp1, Wp2, LWp);
    edge_prep_kernel<<<(N_EDGES_C + 255) / 256, 256, 0, stream>>>(
        node_ids, src, dst, ew, alpha, deg, scale);
    scan1_kernel<<<SCAN_NBLK, SCAN_BLK, 0, stream>>>(deg, bsum);
    scan3_kernel<<<SCAN_NBLK, SCAN_BLK, 0, stream>>>(deg, bsum, rp, cursor);
    csr_fill_part_kernel<<<8 * CSR_GRP_BLKS, 256, 0, stream>>>(
        src, dst, scale, cursor, csr);

    // --- Layer 1 ---
    aggregate_kernel<<<(N_NODES_C * 32) / 256, 256, 0, stream>>>(fbf, rp, csr, neigh_b);
    dense_mfma_kernel<FEATS, true, true><<<N_NODES_C / 32, 128, 0, stream>>>(
        neigh_b, Wp1, b1, h1);

    // --- Layer 2 ---
    aggregate_kernel<<<(N_NODES_C * 32) / 256, 256, 0, stream>>>(h1, rp, csr, neigh_b);
    dense_mfma_kernel<FEATS, true, true><<<N_NODES_C / 32, 128, 0, stream>>>(
        neigh_b, Wp2, b2, h2);

    // --- Classifier ---
    dense_mfma_kernel<NCLS, false, false><<<N_NODES_C / 32, 128, 0, stream>>>(
        h2, LWp, lin_b, out);
}